// Round 11
// baseline (181.068 us; speedup 1.0000x reference)
//
#include <hip/hip_runtime.h>
#include <hip/hip_bf16.h>
#include <math.h>

typedef __bf16 bf16_t;
typedef __attribute__((ext_vector_type(8))) __bf16 bf16x8;
typedef __attribute__((ext_vector_type(4))) __bf16 bf16x4;
typedef __attribute__((ext_vector_type(4))) float f32x4;

#define B_DIM 2
#define S_DIM 2048
#define H_DIM 16
#define DK 64
#define DM 1024
#define KDIM 1024

#define MFMA(a, b, c) __builtin_amdgcn_mfma_f32_16x16x32_bf16((a), (b), (c), 0, 0, 0)

__device__ __forceinline__ void gload_lds16(const bf16_t* g, bf16_t* l) {
    __builtin_amdgcn_global_load_lds(
        (const __attribute__((address_space(1))) void*)g,
        (__attribute__((address_space(3))) void*)l, 16, 0, 0);
}

// ---------------- fp32 -> bf16 convert ----------------
__global__ void cvt_kernel(const float* __restrict__ src, bf16_t* __restrict__ dst, int n) {
    int i = (blockIdx.x * blockDim.x + threadIdx.x) * 4;
    if (i >= n) return;
    float4 v = *reinterpret_cast<const float4*>(src + i);
    bf16x4 o;
    o[0] = (__bf16)v.x; o[1] = (__bf16)v.y; o[2] = (__bf16)v.z; o[3] = (__bf16)v.w;
    *reinterpret_cast<bf16x4*>(dst + i) = o;
}

__global__ void cvt4_kernel(const float* __restrict__ s0, const float* __restrict__ s1,
                            const float* __restrict__ s2, const float* __restrict__ s3,
                            bf16_t* __restrict__ d0, bf16_t* __restrict__ d1,
                            bf16_t* __restrict__ d2, bf16_t* __restrict__ d3, int n) {
    const float* s; bf16_t* d;
    switch (blockIdx.y) {
        case 0: s = s0; d = d0; break;
        case 1: s = s1; d = d1; break;
        case 2: s = s2; d = d2; break;
        default: s = s3; d = d3; break;
    }
    int i = (blockIdx.x * blockDim.x + threadIdx.x) * 4;
    if (i >= n) return;
    float4 v = *reinterpret_cast<const float4*>(s + i);
    bf16x4 o;
    o[0] = (__bf16)v.x; o[1] = (__bf16)v.y; o[2] = (__bf16)v.z; o[3] = (__bf16)v.w;
    *reinterpret_cast<bf16x4*>(d + i) = o;
}

// ---------------- GEMM: Y[m,n] = sum_k A[m,k] * B[n,k]  (B^T layout) ----------------
// (unchanged from R10: 2-sync K-loop + coalesced LDS-staged epilogue w/ fused RoPE)
template <int MODE>
__global__ __launch_bounds__(256)
void gemm_bt(const bf16_t* __restrict__ A,
             const bf16_t* __restrict__ B0,
             const bf16_t* __restrict__ B1,
             const bf16_t* __restrict__ B2,
             bf16_t* __restrict__ outQ,
             bf16_t* __restrict__ outK,
             bf16_t* __restrict__ outVt,
             float* __restrict__ outF,
             const int* __restrict__ pos) {
    constexpr int CP = 136;
    __shared__ bf16_t smem[(MODE == 0) ? (128 * CP) : 8192];
    bf16_t* As = smem;
    bf16_t* Bs = smem + 4096;
    bf16_t* Cs = smem;

    const int t = threadIdx.x;
    const int z = blockIdx.z;
    const bf16_t* Bm = (MODE == 0) ? (z == 0 ? B0 : (z == 1 ? B1 : B2)) : B0;

    const int m0 = blockIdx.x * 128;
    const int n0 = blockIdx.y * 128;
    const int lane = t & 63;
    const int w = t >> 6;
    const int wr = w >> 1;
    const int wc = w & 1;

    f32x4 acc[4][4] = {};

    const int ar = t >> 2;
    const int ac = (t & 3) * 8;
    const bf16_t* Ag = A + (size_t)m0 * KDIM;
    const bf16_t* Bg = Bm + (size_t)n0 * KDIM;

    const int rr = lane & 15;
    const int ko = (lane >> 4) * 8;

    for (int k0 = 0; k0 < KDIM; k0 += 32) {
        gload_lds16(Ag + (size_t)ar * KDIM + k0 + ac,        &As[t * 8]);
        gload_lds16(Ag + (size_t)(ar + 64) * KDIM + k0 + ac, &As[2048 + t * 8]);
        gload_lds16(Bg + (size_t)ar * KDIM + k0 + ac,        &Bs[t * 8]);
        gload_lds16(Bg + (size_t)(ar + 64) * KDIM + k0 + ac, &Bs[2048 + t * 8]);
        __syncthreads();

        bf16x8 af[4], bfr[4];
#pragma unroll
        for (int m = 0; m < 4; ++m)
            af[m] = *reinterpret_cast<const bf16x8*>(&As[(wr * 64 + m * 16 + rr) * 32 + ko]);
#pragma unroll
        for (int n = 0; n < 4; ++n)
            bfr[n] = *reinterpret_cast<const bf16x8*>(&Bs[(wc * 64 + n * 16 + rr) * 32 + ko]);
#pragma unroll
        for (int m = 0; m < 4; ++m)
#pragma unroll
            for (int n = 0; n < 4; ++n)
                acc[m][n] = MFMA(af[m], bfr[n], acc[m][n]);
        __syncthreads();
    }

    const int rlb = wr * 64 + (lane >> 4) * 4;
    const int clb = wc * 64 + (lane & 15);

    if (MODE == 0) {
        if (z < 2) {
#pragma unroll
            for (int m = 0; m < 4; ++m)
#pragma unroll
                for (int n = 0; n < 4; ++n)
#pragma unroll
                    for (int j = 0; j < 4; ++j)
                        Cs[(rlb + m * 16 + j) * CP + clb + n * 16] = (__bf16)acc[m][n][j];
            __syncthreads();

            bf16_t* dst = (z == 0) ? outQ : outK;
            const int dch = t & 7;
            const int srow = t >> 3;
            float fr[4];
#pragma unroll
            for (int i = 0; i < 4; ++i)
                fr[i] = exp2f((float)(dch * 4 + i) * -0.4152410118609203f);
#pragma unroll
            for (int p = 0; p < 4; ++p) {
                const int s_loc = p * 32 + srow;
                const int gm = m0 + s_loc;
                const int bb = gm >> 11, sg = gm & (S_DIM - 1);
                const float pv = (float)pos[sg];
                float csv[4], snv[4];
#pragma unroll
                for (int i = 0; i < 4; ++i) {
                    const float a = pv * fr[i];
                    csv[i] = cosf(a); snv[i] = sinf(a);
                }
#pragma unroll
                for (int hc = 0; hc < 2; ++hc) {
                    const bf16x8 vv = *reinterpret_cast<const bf16x8*>(
                        &Cs[s_loc * CP + hc * 64 + dch * 8]);
                    bf16x8 ov;
#pragma unroll
                    for (int i = 0; i < 4; ++i) {
                        const float v0 = (float)vv[2 * i], v1 = (float)vv[2 * i + 1];
                        ov[2 * i]     = (__bf16)(v0 * csv[i] - v1 * snv[i]);
                        ov[2 * i + 1] = (__bf16)(v0 * snv[i] + v1 * csv[i]);
                    }
                    const int h = (n0 >> 6) + hc;
                    *reinterpret_cast<bf16x8*>(
                        &dst[((size_t)(bb * H_DIM + h) * S_DIM + sg) * 64 + dch * 8]) = ov;
                }
            }
        } else {
#pragma unroll
            for (int m = 0; m < 4; ++m)
#pragma unroll
                for (int n = 0; n < 4; ++n) {
                    const int cl = clb + n * 16;
                    bf16x4 v4;
#pragma unroll
                    for (int j = 0; j < 4; ++j) v4[j] = (__bf16)acc[m][n][j];
                    *reinterpret_cast<bf16x4*>(&Cs[cl * CP + rlb + m * 16]) = v4;
                }
            __syncthreads();

            const int cl = t >> 1, sh = t & 1;
            const int cg = n0 + cl, h = cg >> 6, d = cg & 63;
            const int bb = m0 >> 11, s0g = m0 & (S_DIM - 1);
            bf16_t* vdst = &outVt[((size_t)(bb * H_DIM + h) * DK + d) * S_DIM + s0g + sh * 64];
#pragma unroll
            for (int i = 0; i < 8; ++i)
                *reinterpret_cast<bf16x8*>(&vdst[i * 8]) =
                    *reinterpret_cast<const bf16x8*>(&Cs[cl * CP + sh * 64 + i * 8]);
        }
    } else {
        const int rbase = m0 + rlb;
        const int cbase = n0 + clb;
#pragma unroll
        for (int m = 0; m < 4; ++m)
#pragma unroll
            for (int n = 0; n < 4; ++n)
#pragma unroll
                for (int j = 0; j < 4; ++j)
                    outF[(size_t)(rbase + m * 16 + j) * DM + cbase + n * 16] = acc[m][n][j];
    }
}

// ---------------- causal flash attention v8: 2-wave blocks, 3 blocks/CU ----------
// v7 math, but block = 2 waves owning 32 q-rows of each paired q-block
// (half = blockIdx bit). Grid 1024 -> 3 blocks/CU (LDS 42KB), 12 waves/CU.
__global__ __launch_bounds__(128)
void attn_kernel(const bf16_t* __restrict__ Q, const bf16_t* __restrict__ Kg,
                 const bf16_t* __restrict__ Vt, bf16_t* __restrict__ O) {
    constexpr int PSTR = 72;
    __shared__ bf16_t Ks[2][64 * 64];
    __shared__ bf16_t Vs[2][64 * 64];
    __shared__ bf16_t P_lds[2][2][16 * PSTR];

    const int t = threadIdx.x;
    const int lane = t & 63;
    const int w = t >> 6;                 // 0..1
    const int bh = blockIdx.x >> 5;       // 32 (b,h)
    const int rem = blockIdx.x & 31;
    const int qi = rem >> 1;
    const int half = rem & 1;
    const int qbH = 31 - qi, qbL = qi;
    const int q0H = qbH * 64 + half * 32 + w * 16;
    const int q0L = qbL * 64 + half * 32 + w * 16;
    const int b = bh >> 4, h = bh & 15;
    const int rr = lane & 15;
    const int hi = lane >> 4;

    const bf16_t* Kbh = Kg + (size_t)bh * S_DIM * DK;
    const bf16_t* Vbh = Vt + (size_t)bh * DK * S_DIM;   // [d][s]
    bf16_t* PwH = P_lds[w][0];
    bf16_t* PwL = P_lds[w][1];

    // staging: 512 x 16B chunks per 8KB tile; 128 threads -> 4 chunks each.
    // LDS dest linear; global source pre-swizzled: col ^= (row&7)*8 elems.
    const int i0 = t, i1 = t + 128, i2 = t + 256, i3 = t + 384;
    const int r0 = i0 >> 3, c0 = ((i0 & 7) ^ (r0 & 7)) * 8;
    const int r1 = i1 >> 3, c1 = ((i1 & 7) ^ (r1 & 7)) * 8;
    const int r2 = i2 >> 3, c2 = ((i2 & 7) ^ (r2 & 7)) * 8;
    const int r3 = i3 >> 3, c3 = ((i3 & 7) ^ (r3 & 7)) * 8;

    // Q fragments, folded scale = (1/8) * log2(e)
    const float QSCALE = 0.18033688011112042f;
    const bf16_t* QpH = Q + ((size_t)bh * S_DIM + q0H) * DK;
    const bf16_t* QpL = Q + ((size_t)bh * S_DIM + q0L) * DK;
    bf16x8 qfH[2], qfL[2];
    qfH[0] = *reinterpret_cast<const bf16x8*>(&QpH[rr * DK + hi * 8]);
    qfH[1] = *reinterpret_cast<const bf16x8*>(&QpH[rr * DK + 32 + hi * 8]);
    qfL[0] = *reinterpret_cast<const bf16x8*>(&QpL[rr * DK + hi * 8]);
    qfL[1] = *reinterpret_cast<const bf16x8*>(&QpL[rr * DK + 32 + hi * 8]);
#pragma unroll
    for (int i = 0; i < 8; ++i) {
        qfH[0][i] = (__bf16)((float)qfH[0][i] * QSCALE);
        qfH[1][i] = (__bf16)((float)qfH[1][i] * QSCALE);
        qfL[0][i] = (__bf16)((float)qfL[0][i] * QSCALE);
        qfL[1][i] = (__bf16)((float)qfL[1][i] * QSCALE);
    }

    bf16x8 ones;
#pragma unroll
    for (int i = 0; i < 8; ++i) ones[i] = (__bf16)1.0f;

    f32x4 oH[4] = {}, oL[4] = {};
    f32x4 laH = {}, laL = {};
    float mH = -INFINITY, mL = -INFINITY;

    const int ntH = qbH + 1;

    gload_lds16(Kbh + (size_t)r0 * DK + c0, &Ks[0][i0 * 8]);
    gload_lds16(Kbh + (size_t)r1 * DK + c1, &Ks[0][i1 * 8]);
    gload_lds16(Kbh + (size_t)r2 * DK + c2, &Ks[0][i2 * 8]);
    gload_lds16(Kbh + (size_t)r3 * DK + c3, &Ks[0][i3 * 8]);
    gload_lds16(Vbh + (size_t)r0 * S_DIM + c0, &Vs[0][i0 * 8]);
    gload_lds16(Vbh + (size_t)r1 * S_DIM + c1, &Vs[0][i1 * 8]);
    gload_lds16(Vbh + (size_t)r2 * S_DIM + c2, &Vs[0][i2 * 8]);
    gload_lds16(Vbh + (size_t)r3 * S_DIM + c3, &Vs[0][i3 * 8]);
    __syncthreads();

    for (int tt = 0; tt < ntH; ++tt) {
        const int cur = tt & 1;
        const int kv0 = tt * 64;
        const bool doL = (tt <= qbL);

        if (tt + 1 < ntH) {
            const int kv1 = kv0 + 64;
            bf16_t* Kn = Ks[cur ^ 1];
            bf16_t* Vn = Vs[cur ^ 1];
            gload_lds16(Kbh + (size_t)(kv1 + r0) * DK + c0, &Kn[i0 * 8]);
            gload_lds16(Kbh + (size_t)(kv1 + r1) * DK + c1, &Kn[i1 * 8]);
            gload_lds16(Kbh + (size_t)(kv1 + r2) * DK + c2, &Kn[i2 * 8]);
            gload_lds16(Kbh + (size_t)(kv1 + r3) * DK + c3, &Kn[i3 * 8]);
            gload_lds16(Vbh + (size_t)r0 * S_DIM + kv1 + c0, &Vn[i0 * 8]);
            gload_lds16(Vbh + (size_t)r1 * S_DIM + kv1 + c1, &Vn[i1 * 8]);
            gload_lds16(Vbh + (size_t)r2 * S_DIM + kv1 + c2, &Vn[i2 * 8]);
            gload_lds16(Vbh + (size_t)r3 * S_DIM + kv1 + c3, &Vn[i3 * 8]);
        }
        const bf16_t* Kc = Ks[cur];
        const bf16_t* Vc = Vs[cur];

        f32x4 sH[4] = {}, sL[4] = {};
        __builtin_amdgcn_s_setprio(1);
#pragma unroll
        for (int t16 = 0; t16 < 4; ++t16) {
            const int r = t16 * 16 + rr;
            const int sw = (r & 7) * 8;
            bf16x8 kf0 = *reinterpret_cast<const bf16x8*>(&Kc[r * 64 + ((hi * 8) ^ sw)]);
            bf16x8 kf1 = *reinterpret_cast<const bf16x8*>(&Kc[r * 64 + ((32 + hi * 8) ^ sw)]);
            sH[t16] = MFMA(kf0, qfH[0], sH[t16]);
            sH[t16] = MFMA(kf1, qfH[1], sH[t16]);
            if (doL) {
                sL[t16] = MFMA(kf0, qfL[0], sL[t16]);
                sL[t16] = MFMA(kf1, qfL[1], sL[t16]);
            }
        }
        __builtin_amdgcn_s_setprio(0);

        if (tt == qbH) {
            const int qg = q0H + rr;
#pragma unroll
            for (int t16 = 0; t16 < 4; ++t16)
#pragma unroll
                for (int j = 0; j < 4; ++j)
                    if (kv0 + t16 * 16 + hi * 4 + j > qg) sH[t16][j] = -INFINITY;
        }
        if (tt == qbL) {
            const int qg = q0L + rr;
#pragma unroll
            for (int t16 = 0; t16 < 4; ++t16)
#pragma unroll
                for (int j = 0; j < 4; ++j)
                    if (kv0 + t16 * 16 + hi * 4 + j > qg) sL[t16][j] = -INFINITY;
        }

        // ---- softmax H ----
        {
            f32x4 mv = sH[0];
#pragma unroll
            for (int t16 = 1; t16 < 4; ++t16) {
                mv[0] = fmaxf(mv[0], sH[t16][0]); mv[1] = fmaxf(mv[1], sH[t16][1]);
                mv[2] = fmaxf(mv[2], sH[t16][2]); mv[3] = fmaxf(mv[3], sH[t16][3]);
            }
            const float mloc = fmaxf(fmaxf(mv[0], mv[1]), fmaxf(mv[2], mv[3]));
            if (__any(mloc - mH > 8.0f)) {
                float mf = fmaxf(mloc, __shfl_xor(mloc, 16));
                mf = fmaxf(mf, __shfl_xor(mf, 32));
                const float mnew = fmaxf(mH, mf);
                const float scale = exp2f(mH - mnew);
#pragma unroll
                for (int i = 0; i < 4; ++i) laH[i] *= scale;
#pragma unroll
                for (int db = 0; db < 4; ++db)
#pragma unroll
                    for (int j = 0; j < 4; ++j) oH[db][j] *= scale;
                mH = mnew;
            }
#pragma unroll
            for (int t16 = 0; t16 < 4; ++t16) {
                bf16x4 pb;
#pragma unroll
                for (int j = 0; j < 4; ++j) pb[j] = (__bf16)exp2f(sH[t16][j] - mH);
                *reinterpret_cast<bf16x4*>(&PwH[rr * PSTR + t16 * 16 + hi * 4]) = pb;
            }
        }
        // ---- softmax L ----
        if (doL) {
            f32x4 mv = sL[0];
#pragma unroll
            for (int t16 = 1; t16 < 4; ++t16) {
                mv[0] = fmaxf(mv[0], sL[t16][0]); mv[1] = fmaxf(mv[1], sL[t16][1]);
                mv[2] = fmaxf(mv[2], sL[t16][2]); mv[3] = fmaxf(mv[3], sL[t16][3]);
            }
            const float mloc = fmaxf(fmaxf(mv[0], mv[1]), fmaxf(mv[2], mv[3]));
            if (__any(mloc - mL > 8.0f)) {
                float mf = fmaxf(mloc, __shfl_xor(mloc, 16));
                mf = fmaxf(mf, __shfl_xor(mf, 32));
                const float mnew = fmaxf(mL, mf);
                const float scale = exp2f(mL - mnew);
#pragma unroll
                for (int i = 0; i < 4; ++i) laL[i] *= scale;
#pragma unroll
                for (int db = 0; db < 4; ++db)
#pragma unroll
                    for (int j = 0; j < 4; ++j) oL[db][j] *= scale;
                mL = mnew;
            }
#pragma unroll
            for (int t16 = 0; t16 < 4; ++t16) {
                bf16x4 pb;
#pragma unroll
                for (int j = 0; j < 4; ++j) pb[j] = (__bf16)exp2f(sL[t16][j] - mL);
                *reinterpret_cast<bf16x4*>(&PwL[rr * PSTR + t16 * 16 + hi * 4]) = pb;
            }
        }

        // ---- PV + l via ones-MFMA ----
        bf16x8 pH0 = *reinterpret_cast<const bf16x8*>(&PwH[rr * PSTR + hi * 8]);
        bf16x8 pH1 = *reinterpret_cast<const bf16x8*>(&PwH[rr * PSTR + 32 + hi * 8]);
        bf16x8 pL0, pL1;
        if (doL) {
            pL0 = *reinterpret_cast<const bf16x8*>(&PwL[rr * PSTR + hi * 8]);
            pL1 = *reinterpret_cast<const bf16x8*>(&PwL[rr * PSTR + 32 + hi * 8]);
        }
        __builtin_amdgcn_s_setprio(1);
        laH = MFMA(ones, pH0, laH);
        laH = MFMA(ones, pH1, laH);
        if (doL) {
            laL = MFMA(ones, pL0, laL);
            laL = MFMA(ones, pL1, laL);
        }
#pragma unroll
        for (int db = 0; db < 4; ++db) {
            const int vr = db * 16 + rr;
            const int sw = (vr & 7) * 8;
            bf16x8 vf0 = *reinterpret_cast<const bf16x8*>(&Vc[vr * 64 + ((hi * 8) ^ sw)]);
            bf16x8 vf1 = *reinterpret_cast<const bf16x8*>(&Vc[vr * 64 + ((32 + hi * 8) ^ sw)]);
            oH[db] = MFMA(vf0, pH0, oH[db]);
            oH[db] = MFMA(vf1, pH1, oH[db]);
            if (doL) {
                oL[db] = MFMA(vf0, pL0, oL[db]);
                oL[db] = MFMA(vf1, pL1, oL[db]);
            }
        }
        __builtin_amdgcn_s_setprio(0);

        __syncthreads();
    }

    {
        const float linv = 1.0f / laH[0];
#pragma unroll
        for (int db = 0; db < 4; ++db) {
            bf16x4 ov;
#pragma unroll
            for (int j = 0; j < 4; ++j) ov[j] = (__bf16)(oH[db][j] * linv);
            *reinterpret_cast<bf16x4*>(
                &O[((size_t)(b * S_DIM + q0H + rr)) * DM + h * DK + db * 16 + hi * 4]) = ov;
        }
    }
    {
        const float linv = 1.0f / laL[0];
#pragma unroll
        for (int db = 0; db < 4; ++db) {
            bf16x4 ov;
#pragma unroll
            for (int j = 0; j < 4; ++j) ov[j] = (__bf16)(oL[db][j] * linv);
            *reinterpret_cast<bf16x4*>(
                &O[((size_t)(b * S_DIM + q0L + rr)) * DM + h * DK + db * 16 + hi * 4]) = ov;
        }
    }
}

extern "C" void kernel_launch(void* const* d_in, const int* in_sizes, int n_in,
                              void* d_out, int out_size, void* d_ws, size_t ws_size,
                              hipStream_t stream) {
    const float* x  = (const float*)d_in[0];
    const float* Wq = (const float*)d_in[1];
    const float* Wk = (const float*)d_in[2];
    const float* Wv = (const float*)d_in[3];
    const float* Wo = (const float*)d_in[4];
    const int* pos  = (const int*)d_in[5];
    float* out = (float*)d_out;

    char* ws = (char*)d_ws;
    bf16_t* xb  = (bf16_t*)(ws);
    bf16_t* Wqb = (bf16_t*)(ws + (8u << 20));
    bf16_t* Wkb = (bf16_t*)(ws + (10u << 20));
    bf16_t* Wvb = (bf16_t*)(ws + (12u << 20));
    bf16_t* Wob = (bf16_t*)(ws + (14u << 20));
    bf16_t* Qb  = (bf16_t*)(ws + (16u << 20));
    bf16_t* Kb  = (bf16_t*)(ws + (24u << 20));
    bf16_t* Vtb = (bf16_t*)(ws + (32u << 20));
    bf16_t* Ab  = (bf16_t*)(ws);  // reuse xb region after QKV GEMM

    const int NX = B_DIM * S_DIM * DM;
    const int NW = DM * DM;

    cvt_kernel<<<NX / 1024, 256, 0, stream>>>(x, xb, NX);
    cvt4_kernel<<<dim3(NW / 1024, 4), 256, 0, stream>>>(Wq, Wk, Wv, Wo,
                                                        Wqb, Wkb, Wvb, Wob, NW);

    gemm_bt<0><<<dim3(32, 8, 3), 256, 0, stream>>>(xb, Wqb, Wkb, Wvb,
                                                   Qb, Kb, Vtb, nullptr, pos);

    attn_kernel<<<B_DIM * H_DIM * 32, 128, 0, stream>>>(Qb, Kb, Vtb, Ab);

    gemm_bt<1><<<dim3(32, 8, 1), 256, 0, stream>>>(Ab, Wob, nullptr, nullptr,
                                                   nullptr, nullptr, nullptr, out, pos);
}

// Round 12
// 129.809 us; speedup vs baseline: 1.3949x; 1.3949x over previous
//
#include <hip/hip_runtime.h>
#include <hip/hip_bf16.h>
#include <math.h>

typedef __bf16 bf16_t;
typedef __attribute__((ext_vector_type(8))) __bf16 bf16x8;
typedef __attribute__((ext_vector_type(4))) __bf16 bf16x4;
typedef __attribute__((ext_vector_type(4))) float f32x4;

#define B_DIM 2
#define S_DIM 2048
#define H_DIM 16
#define DK 64
#define DM 1024
#define KDIM 1024

#define MFMA(a, b, c) __builtin_amdgcn_mfma_f32_16x16x32_bf16((a), (b), (c), 0, 0, 0)

__device__ __forceinline__ void gload_lds16(const bf16_t* g, bf16_t* l) {
    __builtin_amdgcn_global_load_lds(
        (const __attribute__((address_space(1))) void*)g,
        (__attribute__((address_space(3))) void*)l, 16, 0, 0);
}

// ---------------- fp32 -> bf16 convert: x + 4 weights in ONE launch ----------------
__global__ void cvt_all(const float* __restrict__ x,
                        const float* __restrict__ wq, const float* __restrict__ wk,
                        const float* __restrict__ wv, const float* __restrict__ wo,
                        bf16_t* __restrict__ xb,
                        bf16_t* __restrict__ wqb, bf16_t* __restrict__ wkb,
                        bf16_t* __restrict__ wvb, bf16_t* __restrict__ wob) {
    const long NX = (long)B_DIM * S_DIM * DM;       // 4194304
    const long i = ((long)blockIdx.x * 256 + threadIdx.x) * 4;
    const float* s; bf16_t* d; long off;
    if (i < NX) { s = x; d = xb; off = i; }
    else {
        const long j = i - NX;
        const int wsel = (int)(j >> 20);            // NW = 1<<20
        off = j & ((1L << 20) - 1);
        switch (wsel) {
            case 0: s = wq; d = wqb; break;
            case 1: s = wk; d = wkb; break;
            case 2: s = wv; d = wvb; break;
            default: s = wo; d = wob; break;
        }
    }
    float4 v = *reinterpret_cast<const float4*>(s + off);
    bf16x4 o;
    o[0] = (__bf16)v.x; o[1] = (__bf16)v.y; o[2] = (__bf16)v.z; o[3] = (__bf16)v.w;
    *reinterpret_cast<bf16x4*>(d + off) = o;
}

// ---------------- GEMM: Y[m,n] = sum_k A[m,k] * B[n,k]  (B^T layout) ----------------
// BK=64 K-loop (16 iters, 32 MFMA/iter), XOR-swizzled LDS tiles (attn-proven
// pattern: 64-elem rows, col ^= (row&7)*8 via pre-swizzled global source).
// 2-sync per iter. Epilogues unchanged from R10 (coalesced LDS-staged writeout,
// RoPE fused on Q/K readout).
template <int MODE>
__global__ __launch_bounds__(256)
void gemm_bt(const bf16_t* __restrict__ A,
             const bf16_t* __restrict__ B0,
             const bf16_t* __restrict__ B1,
             const bf16_t* __restrict__ B2,
             bf16_t* __restrict__ outQ,
             bf16_t* __restrict__ outK,
             bf16_t* __restrict__ outVt,
             float* __restrict__ outF,
             const int* __restrict__ pos) {
    constexpr int CP = 136;
    constexpr int SELEMS = (MODE == 0) ? (128 * CP) : 16384;
    __shared__ bf16_t smem[SELEMS];
    bf16_t* As = smem;            // [128][64] swizzled
    bf16_t* Bs = smem + 8192;     // [128][64] swizzled
    bf16_t* Cs = smem;            // epilogue overlay

    const int t = threadIdx.x;
    const int z = blockIdx.z;
    const bf16_t* Bm = (MODE == 0) ? (z == 0 ? B0 : (z == 1 ? B1 : B2)) : B0;

    const int m0 = blockIdx.x * 128;
    const int n0 = blockIdx.y * 128;
    const int lane = t & 63;
    const int w = t >> 6;
    const int wr = w >> 1;
    const int wc = w & 1;

    f32x4 acc[4][4] = {};

    const bf16_t* Ag = A + (size_t)m0 * KDIM;
    const bf16_t* Bg = Bm + (size_t)n0 * KDIM;

    const int rr = lane & 15;
    const int ko = (lane >> 4) * 8;

    // staging geometry: 1024 x 16B chunks per 16KB tile; thread t does 4 chunks.
    // LDS dest linear; global source pre-swizzled: col ^= (row&7)*8 elems.
    int rI[4], cI[4];
#pragma unroll
    for (int c = 0; c < 4; ++c) {
        const int i = t + c * 256;
        rI[c] = i >> 3;
        cI[c] = ((i & 7) ^ (rI[c] & 7)) * 8;
    }

    for (int k0 = 0; k0 < KDIM; k0 += 64) {
#pragma unroll
        for (int c = 0; c < 4; ++c) {
            const int i = t + c * 256;
            gload_lds16(Ag + (size_t)rI[c] * KDIM + k0 + cI[c], &As[i * 8]);
        }
#pragma unroll
        for (int c = 0; c < 4; ++c) {
            const int i = t + c * 256;
            gload_lds16(Bg + (size_t)rI[c] * KDIM + k0 + cI[c], &Bs[i * 8]);
        }
        __syncthreads();

        bf16x8 af[2][4], bfr[2][4];
#pragma unroll
        for (int kk = 0; kk < 2; ++kk) {
#pragma unroll
            for (int m = 0; m < 4; ++m) {
                const int r = wr * 64 + m * 16 + rr;
                af[kk][m] = *reinterpret_cast<const bf16x8*>(
                    &As[r * 64 + ((kk * 32 + ko) ^ ((r & 7) * 8))]);
            }
#pragma unroll
            for (int n = 0; n < 4; ++n) {
                const int r = wc * 64 + n * 16 + rr;
                bfr[kk][n] = *reinterpret_cast<const bf16x8*>(
                    &Bs[r * 64 + ((kk * 32 + ko) ^ ((r & 7) * 8))]);
            }
        }
        __builtin_amdgcn_s_setprio(1);
#pragma unroll
        for (int kk = 0; kk < 2; ++kk)
#pragma unroll
            for (int m = 0; m < 4; ++m)
#pragma unroll
                for (int n = 0; n < 4; ++n)
                    acc[m][n] = MFMA(af[kk][m], bfr[kk][n], acc[m][n]);
        __builtin_amdgcn_s_setprio(0);
        __syncthreads();
    }

    const int rlb = wr * 64 + (lane >> 4) * 4;
    const int clb = wc * 64 + (lane & 15);

    if (MODE == 0) {
        if (z < 2) {
#pragma unroll
            for (int m = 0; m < 4; ++m)
#pragma unroll
                for (int n = 0; n < 4; ++n)
#pragma unroll
                    for (int j = 0; j < 4; ++j)
                        Cs[(rlb + m * 16 + j) * CP + clb + n * 16] = (__bf16)acc[m][n][j];
            __syncthreads();

            bf16_t* dst = (z == 0) ? outQ : outK;
            const int dch = t & 7;
            const int srow = t >> 3;
            float fr[4];
#pragma unroll
            for (int i = 0; i < 4; ++i)
                fr[i] = exp2f((float)(dch * 4 + i) * -0.4152410118609203f);
#pragma unroll
            for (int p = 0; p < 4; ++p) {
                const int s_loc = p * 32 + srow;
                const int gm = m0 + s_loc;
                const int bb = gm >> 11, sg = gm & (S_DIM - 1);
                const float pv = (float)pos[sg];
                float csv[4], snv[4];
#pragma unroll
                for (int i = 0; i < 4; ++i) {
                    const float a = pv * fr[i];
                    csv[i] = cosf(a); snv[i] = sinf(a);
                }
#pragma unroll
                for (int hc = 0; hc < 2; ++hc) {
                    const bf16x8 vv = *reinterpret_cast<const bf16x8*>(
                        &Cs[s_loc * CP + hc * 64 + dch * 8]);
                    bf16x8 ov;
#pragma unroll
                    for (int i = 0; i < 4; ++i) {
                        const float v0 = (float)vv[2 * i], v1 = (float)vv[2 * i + 1];
                        ov[2 * i]     = (__bf16)(v0 * csv[i] - v1 * snv[i]);
                        ov[2 * i + 1] = (__bf16)(v0 * snv[i] + v1 * csv[i]);
                    }
                    const int h = (n0 >> 6) + hc;
                    *reinterpret_cast<bf16x8*>(
                        &dst[((size_t)(bb * H_DIM + h) * S_DIM + sg) * 64 + dch * 8]) = ov;
                }
            }
        } else {
#pragma unroll
            for (int m = 0; m < 4; ++m)
#pragma unroll
                for (int n = 0; n < 4; ++n) {
                    const int cl = clb + n * 16;
                    bf16x4 v4;
#pragma unroll
                    for (int j = 0; j < 4; ++j) v4[j] = (__bf16)acc[m][n][j];
                    *reinterpret_cast<bf16x4*>(&Cs[cl * CP + rlb + m * 16]) = v4;
                }
            __syncthreads();

            const int cl = t >> 1, sh = t & 1;
            const int cg = n0 + cl, h = cg >> 6, d = cg & 63;
            const int bb = m0 >> 11, s0g = m0 & (S_DIM - 1);
            bf16_t* vdst = &outVt[((size_t)(bb * H_DIM + h) * DK + d) * S_DIM + s0g + sh * 64];
#pragma unroll
            for (int i = 0; i < 8; ++i)
                *reinterpret_cast<bf16x8*>(&vdst[i * 8]) =
                    *reinterpret_cast<const bf16x8*>(&Cs[cl * CP + sh * 64 + i * 8]);
        }
    } else {
        const int rbase = m0 + rlb;
        const int cbase = n0 + clb;
#pragma unroll
        for (int m = 0; m < 4; ++m)
#pragma unroll
            for (int n = 0; n < 4; ++n)
#pragma unroll
                for (int j = 0; j < 4; ++j)
                    outF[(size_t)(rbase + m * 16 + j) * DM + cbase + n * 16] = acc[m][n][j];
    }
}

// ---------------- causal flash attention v7 (R10-exact, proven 67 us) ----------------
__global__ __launch_bounds__(256)
void attn_kernel(const bf16_t* __restrict__ Q, const bf16_t* __restrict__ Kg,
                 const bf16_t* __restrict__ Vt, bf16_t* __restrict__ O) {
    constexpr int PSTR = 72;
    __shared__ bf16_t Ks[2][64 * 64];
    __shared__ bf16_t Vs[2][64 * 64];
    __shared__ bf16_t P_lds[4][2][16 * PSTR];

    const int t = threadIdx.x;
    const int lane = t & 63;
    const int w = t >> 6;
    const int bh = blockIdx.x >> 4;
    const int qi = blockIdx.x & 15;
    const int qbH = 31 - qi, qbL = qi;
    const int q0H = qbH * 64 + w * 16;
    const int q0L = qbL * 64 + w * 16;
    const int b = bh >> 4, h = bh & 15;
    const int rr = lane & 15;
    const int hi = lane >> 4;

    const bf16_t* Kbh = Kg + (size_t)bh * S_DIM * DK;
    const bf16_t* Vbh = Vt + (size_t)bh * DK * S_DIM;
    bf16_t* PwH = P_lds[w][0];
    bf16_t* PwL = P_lds[w][1];

    const int i0 = t, i1 = t + 256;
    const int r0 = i0 >> 3, c0 = ((i0 & 7) ^ (r0 & 7)) * 8;
    const int r1 = i1 >> 3, c1 = ((i1 & 7) ^ (r1 & 7)) * 8;

    const float QSCALE = 0.18033688011112042f;
    const bf16_t* QpH = Q + ((size_t)bh * S_DIM + q0H) * DK;
    const bf16_t* QpL = Q + ((size_t)bh * S_DIM + q0L) * DK;
    bf16x8 qfH[2], qfL[2];
    qfH[0] = *reinterpret_cast<const bf16x8*>(&QpH[rr * DK + hi * 8]);
    qfH[1] = *reinterpret_cast<const bf16x8*>(&QpH[rr * DK + 32 + hi * 8]);
    qfL[0] = *reinterpret_cast<const bf16x8*>(&QpL[rr * DK + hi * 8]);
    qfL[1] = *reinterpret_cast<const bf16x8*>(&QpL[rr * DK + 32 + hi * 8]);
#pragma unroll
    for (int i = 0; i < 8; ++i) {
        qfH[0][i] = (__bf16)((float)qfH[0][i] * QSCALE);
        qfH[1][i] = (__bf16)((float)qfH[1][i] * QSCALE);
        qfL[0][i] = (__bf16)((float)qfL[0][i] * QSCALE);
        qfL[1][i] = (__bf16)((float)qfL[1][i] * QSCALE);
    }

    bf16x8 ones;
#pragma unroll
    for (int i = 0; i < 8; ++i) ones[i] = (__bf16)1.0f;

    f32x4 oH[4] = {}, oL[4] = {};
    f32x4 laH = {}, laL = {};
    float mH = -INFINITY, mL = -INFINITY;

    const int ntH = qbH + 1;

    gload_lds16(Kbh + (size_t)r0 * DK + c0, &Ks[0][i0 * 8]);
    gload_lds16(Kbh + (size_t)r1 * DK + c1, &Ks[0][i1 * 8]);
    gload_lds16(Vbh + (size_t)r0 * S_DIM + c0, &Vs[0][i0 * 8]);
    gload_lds16(Vbh + (size_t)r1 * S_DIM + c1, &Vs[0][i1 * 8]);
    __syncthreads();

    for (int tt = 0; tt < ntH; ++tt) {
        const int cur = tt & 1;
        const int kv0 = tt * 64;
        const bool doL = (tt <= qbL);

        if (tt + 1 < ntH) {
            const int kv1 = kv0 + 64;
            bf16_t* Kn = Ks[cur ^ 1];
            bf16_t* Vn = Vs[cur ^ 1];
            gload_lds16(Kbh + (size_t)(kv1 + r0) * DK + c0, &Kn[i0 * 8]);
            gload_lds16(Kbh + (size_t)(kv1 + r1) * DK + c1, &Kn[i1 * 8]);
            gload_lds16(Vbh + (size_t)r0 * S_DIM + kv1 + c0, &Vn[i0 * 8]);
            gload_lds16(Vbh + (size_t)r1 * S_DIM + kv1 + c1, &Vn[i1 * 8]);
        }
        const bf16_t* Kc = Ks[cur];
        const bf16_t* Vc = Vs[cur];

        f32x4 sH[4] = {}, sL[4] = {};
        __builtin_amdgcn_s_setprio(1);
#pragma unroll
        for (int t16 = 0; t16 < 4; ++t16) {
            const int r = t16 * 16 + rr;
            const int sw = (r & 7) * 8;
            bf16x8 kf0 = *reinterpret_cast<const bf16x8*>(&Kc[r * 64 + ((hi * 8) ^ sw)]);
            bf16x8 kf1 = *reinterpret_cast<const bf16x8*>(&Kc[r * 64 + ((32 + hi * 8) ^ sw)]);
            sH[t16] = MFMA(kf0, qfH[0], sH[t16]);
            sH[t16] = MFMA(kf1, qfH[1], sH[t16]);
            if (doL) {
                sL[t16] = MFMA(kf0, qfL[0], sL[t16]);
                sL[t16] = MFMA(kf1, qfL[1], sL[t16]);
            }
        }
        __builtin_amdgcn_s_setprio(0);

        if (tt == qbH) {
            const int qg = q0H + rr;
#pragma unroll
            for (int t16 = 0; t16 < 4; ++t16)
#pragma unroll
                for (int j = 0; j < 4; ++j)
                    if (kv0 + t16 * 16 + hi * 4 + j > qg) sH[t16][j] = -INFINITY;
        }
        if (tt == qbL) {
            const int qg = q0L + rr;
#pragma unroll
            for (int t16 = 0; t16 < 4; ++t16)
#pragma unroll
                for (int j = 0; j < 4; ++j)
                    if (kv0 + t16 * 16 + hi * 4 + j > qg) sL[t16][j] = -INFINITY;
        }

        {
            f32x4 mv = sH[0];
#pragma unroll
            for (int t16 = 1; t16 < 4; ++t16) {
                mv[0] = fmaxf(mv[0], sH[t16][0]); mv[1] = fmaxf(mv[1], sH[t16][1]);
                mv[2] = fmaxf(mv[2], sH[t16][2]); mv[3] = fmaxf(mv[3], sH[t16][3]);
            }
            const float mloc = fmaxf(fmaxf(mv[0], mv[1]), fmaxf(mv[2], mv[3]));
            if (__any(mloc - mH > 8.0f)) {
                float mf = fmaxf(mloc, __shfl_xor(mloc, 16));
                mf = fmaxf(mf, __shfl_xor(mf, 32));
                const float mnew = fmaxf(mH, mf);
                const float scale = exp2f(mH - mnew);
#pragma unroll
                for (int i = 0; i < 4; ++i) laH[i] *= scale;
#pragma unroll
                for (int db = 0; db < 4; ++db)
#pragma unroll
                    for (int j = 0; j < 4; ++j) oH[db][j] *= scale;
                mH = mnew;
            }
#pragma unroll
            for (int t16 = 0; t16 < 4; ++t16) {
                bf16x4 pb;
#pragma unroll
                for (int j = 0; j < 4; ++j) pb[j] = (__bf16)exp2f(sH[t16][j] - mH);
                *reinterpret_cast<bf16x4*>(&PwH[rr * PSTR + t16 * 16 + hi * 4]) = pb;
            }
        }
        if (doL) {
            f32x4 mv = sL[0];
#pragma unroll
            for (int t16 = 1; t16 < 4; ++t16) {
                mv[0] = fmaxf(mv[0], sL[t16][0]); mv[1] = fmaxf(mv[1], sL[t16][1]);
                mv[2] = fmaxf(mv[2], sL[t16][2]); mv[3] = fmaxf(mv[3], sL[t16][3]);
            }
            const float mloc = fmaxf(fmaxf(mv[0], mv[1]), fmaxf(mv[2], mv[3]));
            if (__any(mloc - mL > 8.0f)) {
                float mf = fmaxf(mloc, __shfl_xor(mloc, 16));
                mf = fmaxf(mf, __shfl_xor(mf, 32));
                const float mnew = fmaxf(mL, mf);
                const float scale = exp2f(mL - mnew);
#pragma unroll
                for (int i = 0; i < 4; ++i) laL[i] *= scale;
#pragma unroll
                for (int db = 0; db < 4; ++db)
#pragma unroll
                    for (int j = 0; j < 4; ++j) oL[db][j] *= scale;
                mL = mnew;
            }
#pragma unroll
            for (int t16 = 0; t16 < 4; ++t16) {
                bf16x4 pb;
#pragma unroll
                for (int j = 0; j < 4; ++j) pb[j] = (__bf16)exp2f(sL[t16][j] - mL);
                *reinterpret_cast<bf16x4*>(&PwL[rr * PSTR + t16 * 16 + hi * 4]) = pb;
            }
        }

        bf16x8 pH0 = *reinterpret_cast<const bf16x8*>(&PwH[rr * PSTR + hi * 8]);
        bf16x8 pH1 = *reinterpret_cast<const bf16x8*>(&PwH[rr * PSTR + 32 + hi * 8]);
        bf16x8 pL0, pL1;
        if (doL) {
            pL0 = *reinterpret_cast<const bf16x8*>(&PwL[rr * PSTR + hi * 8]);
            pL1 = *reinterpret_cast<const bf16x8*>(&PwL[rr * PSTR + 32 + hi * 8]);
        }
        __builtin_amdgcn_s_setprio(1);
        laH = MFMA(ones, pH0, laH);
        laH = MFMA(ones, pH1, laH);
        if (doL) {
            laL = MFMA(ones, pL0, laL);
            laL = MFMA(ones, pL1, laL);
        }
#pragma unroll
        for (int db = 0; db < 4; ++db) {
            const int vr = db * 16 + rr;
            const int sw = (vr & 7) * 8;
            bf16x8 vf0 = *reinterpret_cast<const bf16x8*>(&Vc[vr * 64 + ((hi * 8) ^ sw)]);
            bf16x8 vf1 = *reinterpret_cast<const bf16x8*>(&Vc[vr * 64 + ((32 + hi * 8) ^ sw)]);
            oH[db] = MFMA(vf0, pH0, oH[db]);
            oH[db] = MFMA(vf1, pH1, oH[db]);
            if (doL) {
                oL[db] = MFMA(vf0, pL0, oL[db]);
                oL[db] = MFMA(vf1, pL1, oL[db]);
            }
        }
        __builtin_amdgcn_s_setprio(0);

        __syncthreads();
    }

    {
        const float linv = 1.0f / laH[0];
#pragma unroll
        for (int db = 0; db < 4; ++db) {
            bf16x4 ov;
#pragma unroll
            for (int j = 0; j < 4; ++j) ov[j] = (__bf16)(oH[db][j] * linv);
            *reinterpret_cast<bf16x4*>(
                &O[((size_t)(b * S_DIM + q0H + rr)) * DM + h * DK + db * 16 + hi * 4]) = ov;
        }
    }
    {
        const float linv = 1.0f / laL[0];
#pragma unroll
        for (int db = 0; db < 4; ++db) {
            bf16x4 ov;
#pragma unroll
            for (int j = 0; j < 4; ++j) ov[j] = (__bf16)(oL[db][j] * linv);
            *reinterpret_cast<bf16x4*>(
                &O[((size_t)(b * S_DIM + q0L + rr)) * DM + h * DK + db * 16 + hi * 4]) = ov;
        }
    }
}

extern "C" void kernel_launch(void* const* d_in, const int* in_sizes, int n_in,
                              void* d_out, int out_size, void* d_ws, size_t ws_size,
                              hipStream_t stream) {
    const float* x  = (const float*)d_in[0];
    const float* Wq = (const float*)d_in[1];
    const float* Wk = (const float*)d_in[2];
    const float* Wv = (const float*)d_in[3];
    const float* Wo = (const float*)d_in[4];
    const int* pos  = (const int*)d_in[5];
    float* out = (float*)d_out;

    char* ws = (char*)d_ws;
    bf16_t* xb  = (bf16_t*)(ws);
    bf16_t* Wqb = (bf16_t*)(ws + (8u << 20));
    bf16_t* Wkb = (bf16_t*)(ws + (10u << 20));
    bf16_t* Wvb = (bf16_t*)(ws + (12u << 20));
    bf16_t* Wob = (bf16_t*)(ws + (14u << 20));
    bf16_t* Qb  = (bf16_t*)(ws + (16u << 20));
    bf16_t* Kb  = (bf16_t*)(ws + (24u << 20));
    bf16_t* Vtb = (bf16_t*)(ws + (32u << 20));
    bf16_t* Ab  = (bf16_t*)(ws);  // reuse xb region after QKV GEMM

    const int NX = B_DIM * S_DIM * DM;
    const int NW = DM * DM;
    const int NTOT = NX + 4 * NW;  // 8388608

    cvt_all<<<NTOT / 1024, 256, 0, stream>>>(x, Wq, Wk, Wv, Wo,
                                             xb, Wqb, Wkb, Wvb, Wob);

    gemm_bt<0><<<dim3(32, 8, 3), 256, 0, stream>>>(xb, Wqb, Wkb, Wvb,
                                                   Qb, Kb, Vtb, nullptr, pos);

    attn_kernel<<<B_DIM * H_DIM * 16, 256, 0, stream>>>(Qb, Kb, Vtb, Ab);

    gemm_bt<1><<<dim3(32, 8, 1), 256, 0, stream>>>(Ab, Wob, nullptr, nullptr,
                                                   nullptr, nullptr, nullptr, out, pos);
}

// Round 13
// 113.927 us; speedup vs baseline: 1.5893x; 1.1394x over previous
//
#include <hip/hip_runtime.h>
#include <hip/hip_bf16.h>
#include <math.h>

typedef __bf16 bf16_t;
typedef __attribute__((ext_vector_type(8))) __bf16 bf16x8;
typedef __attribute__((ext_vector_type(4))) __bf16 bf16x4;
typedef __attribute__((ext_vector_type(4))) float f32x4;

#define B_DIM 2
#define S_DIM 2048
#define H_DIM 16
#define DK 64
#define DM 1024
#define KDIM 1024

#define MFMA(a, b, c) __builtin_amdgcn_mfma_f32_16x16x32_bf16((a), (b), (c), 0, 0, 0)

__device__ __forceinline__ void gload_lds16(const bf16_t* g, bf16_t* l) {
    __builtin_amdgcn_global_load_lds(
        (const __attribute__((address_space(1))) void*)g,
        (__attribute__((address_space(3))) void*)l, 16, 0, 0);
}

// ---------------- fp32 -> bf16 convert: x + 4 weights in ONE launch ----------------
__global__ void cvt_all(const float* __restrict__ x,
                        const float* __restrict__ wq, const float* __restrict__ wk,
                        const float* __restrict__ wv, const float* __restrict__ wo,
                        bf16_t* __restrict__ xb,
                        bf16_t* __restrict__ wqb, bf16_t* __restrict__ wkb,
                        bf16_t* __restrict__ wvb, bf16_t* __restrict__ wob) {
    const long NX = (long)B_DIM * S_DIM * DM;       // 4194304
    const long i = ((long)blockIdx.x * 256 + threadIdx.x) * 4;
    const float* s; bf16_t* d; long off;
    if (i < NX) { s = x; d = xb; off = i; }
    else {
        const long j = i - NX;
        const int wsel = (int)(j >> 20);            // NW = 1<<20
        off = j & ((1L << 20) - 1);
        switch (wsel) {
            case 0: s = wq; d = wqb; break;
            case 1: s = wk; d = wkb; break;
            case 2: s = wv; d = wvb; break;
            default: s = wo; d = wob; break;
        }
    }
    float4 v = *reinterpret_cast<const float4*>(s + off);
    bf16x4 o;
    o[0] = (__bf16)v.x; o[1] = (__bf16)v.y; o[2] = (__bf16)v.z; o[3] = (__bf16)v.w;
    *reinterpret_cast<bf16x4*>(d + off) = o;
}

// ---------------- GEMM: Y[m,n] = sum_k A[m,k] * B[n,k]  (B^T layout) ----------------
// (unchanged from R12: BK=64 XOR-swizzled K-loop + coalesced epilogues)
template <int MODE>
__global__ __launch_bounds__(256)
void gemm_bt(const bf16_t* __restrict__ A,
             const bf16_t* __restrict__ B0,
             const bf16_t* __restrict__ B1,
             const bf16_t* __restrict__ B2,
             bf16_t* __restrict__ outQ,
             bf16_t* __restrict__ outK,
             bf16_t* __restrict__ outVt,
             float* __restrict__ outF,
             const int* __restrict__ pos) {
    constexpr int CP = 136;
    constexpr int SELEMS = (MODE == 0) ? (128 * CP) : 16384;
    __shared__ bf16_t smem[SELEMS];
    bf16_t* As = smem;            // [128][64] swizzled
    bf16_t* Bs = smem + 8192;     // [128][64] swizzled
    bf16_t* Cs = smem;            // epilogue overlay

    const int t = threadIdx.x;
    const int z = blockIdx.z;
    const bf16_t* Bm = (MODE == 0) ? (z == 0 ? B0 : (z == 1 ? B1 : B2)) : B0;

    const int m0 = blockIdx.x * 128;
    const int n0 = blockIdx.y * 128;
    const int lane = t & 63;
    const int w = t >> 6;
    const int wr = w >> 1;
    const int wc = w & 1;

    f32x4 acc[4][4] = {};

    const bf16_t* Ag = A + (size_t)m0 * KDIM;
    const bf16_t* Bg = Bm + (size_t)n0 * KDIM;

    const int rr = lane & 15;
    const int ko = (lane >> 4) * 8;

    int rI[4], cI[4];
#pragma unroll
    for (int c = 0; c < 4; ++c) {
        const int i = t + c * 256;
        rI[c] = i >> 3;
        cI[c] = ((i & 7) ^ (rI[c] & 7)) * 8;
    }

    for (int k0 = 0; k0 < KDIM; k0 += 64) {
#pragma unroll
        for (int c = 0; c < 4; ++c) {
            const int i = t + c * 256;
            gload_lds16(Ag + (size_t)rI[c] * KDIM + k0 + cI[c], &As[i * 8]);
        }
#pragma unroll
        for (int c = 0; c < 4; ++c) {
            const int i = t + c * 256;
            gload_lds16(Bg + (size_t)rI[c] * KDIM + k0 + cI[c], &Bs[i * 8]);
        }
        __syncthreads();

        bf16x8 af[2][4], bfr[2][4];
#pragma unroll
        for (int kk = 0; kk < 2; ++kk) {
#pragma unroll
            for (int m = 0; m < 4; ++m) {
                const int r = wr * 64 + m * 16 + rr;
                af[kk][m] = *reinterpret_cast<const bf16x8*>(
                    &As[r * 64 + ((kk * 32 + ko) ^ ((r & 7) * 8))]);
            }
#pragma unroll
            for (int n = 0; n < 4; ++n) {
                const int r = wc * 64 + n * 16 + rr;
                bfr[kk][n] = *reinterpret_cast<const bf16x8*>(
                    &Bs[r * 64 + ((kk * 32 + ko) ^ ((r & 7) * 8))]);
            }
        }
        __builtin_amdgcn_s_setprio(1);
#pragma unroll
        for (int kk = 0; kk < 2; ++kk)
#pragma unroll
            for (int m = 0; m < 4; ++m)
#pragma unroll
                for (int n = 0; n < 4; ++n)
                    acc[m][n] = MFMA(af[kk][m], bfr[kk][n], acc[m][n]);
        __builtin_amdgcn_s_setprio(0);
        __syncthreads();
    }

    const int rlb = wr * 64 + (lane >> 4) * 4;
    const int clb = wc * 64 + (lane & 15);

    if (MODE == 0) {
        if (z < 2) {
#pragma unroll
            for (int m = 0; m < 4; ++m)
#pragma unroll
                for (int n = 0; n < 4; ++n)
#pragma unroll
                    for (int j = 0; j < 4; ++j)
                        Cs[(rlb + m * 16 + j) * CP + clb + n * 16] = (__bf16)acc[m][n][j];
            __syncthreads();

            bf16_t* dst = (z == 0) ? outQ : outK;
            const int dch = t & 7;
            const int srow = t >> 3;
            float fr[4];
#pragma unroll
            for (int i = 0; i < 4; ++i)
                fr[i] = exp2f((float)(dch * 4 + i) * -0.4152410118609203f);
#pragma unroll
            for (int p = 0; p < 4; ++p) {
                const int s_loc = p * 32 + srow;
                const int gm = m0 + s_loc;
                const int bb = gm >> 11, sg = gm & (S_DIM - 1);
                const float pv = (float)pos[sg];
                float csv[4], snv[4];
#pragma unroll
                for (int i = 0; i < 4; ++i) {
                    const float a = pv * fr[i];
                    csv[i] = cosf(a); snv[i] = sinf(a);
                }
#pragma unroll
                for (int hc = 0; hc < 2; ++hc) {
                    const bf16x8 vv = *reinterpret_cast<const bf16x8*>(
                        &Cs[s_loc * CP + hc * 64 + dch * 8]);
                    bf16x8 ov;
#pragma unroll
                    for (int i = 0; i < 4; ++i) {
                        const float v0 = (float)vv[2 * i], v1 = (float)vv[2 * i + 1];
                        ov[2 * i]     = (__bf16)(v0 * csv[i] - v1 * snv[i]);
                        ov[2 * i + 1] = (__bf16)(v0 * snv[i] + v1 * csv[i]);
                    }
                    const int h = (n0 >> 6) + hc;
                    *reinterpret_cast<bf16x8*>(
                        &dst[((size_t)(bb * H_DIM + h) * S_DIM + sg) * 64 + dch * 8]) = ov;
                }
            }
        } else {
#pragma unroll
            for (int m = 0; m < 4; ++m)
#pragma unroll
                for (int n = 0; n < 4; ++n) {
                    const int cl = clb + n * 16;
                    bf16x4 v4;
#pragma unroll
                    for (int j = 0; j < 4; ++j) v4[j] = (__bf16)acc[m][n][j];
                    *reinterpret_cast<bf16x4*>(&Cs[cl * CP + rlb + m * 16]) = v4;
                }
            __syncthreads();

            const int cl = t >> 1, sh = t & 1;
            const int cg = n0 + cl, h = cg >> 6, d = cg & 63;
            const int bb = m0 >> 11, s0g = m0 & (S_DIM - 1);
            bf16_t* vdst = &outVt[((size_t)(bb * H_DIM + h) * DK + d) * S_DIM + s0g + sh * 64];
#pragma unroll
            for (int i = 0; i < 8; ++i)
                *reinterpret_cast<bf16x8*>(&vdst[i * 8]) =
                    *reinterpret_cast<const bf16x8*>(&Cs[cl * CP + sh * 64 + i * 8]);
        }
    } else {
        const int rbase = m0 + rlb;
        const int cbase = n0 + clb;
#pragma unroll
        for (int m = 0; m < 4; ++m)
#pragma unroll
            for (int n = 0; n < 4; ++n)
#pragma unroll
                for (int j = 0; j < 4; ++j)
                    outF[(size_t)(rbase + m * 16 + j) * DM + cbase + n * 16] = acc[m][n][j];
    }
}

// ---------------- causal flash attention v9: 8 waves, 1 chain/wave ----------------
// Same pairing (qbH=31-qi, qbL=qi) and K/V dbuf XOR-swizzled LDS as v7, but
// block = 512 threads / 8 waves: waves 0-3 run the H chain (16 rows each),
// waves 4-7 the L chain. 2 blocks/CU x 8 waves = 16 waves/CU (ILP -> TLP).
// L-waves idle at the barrier once tt > qbL (no issue cost); all waves stage.
__global__ __launch_bounds__(512, 4)
void attn_kernel(const bf16_t* __restrict__ Q, const bf16_t* __restrict__ Kg,
                 const bf16_t* __restrict__ Vt, bf16_t* __restrict__ O) {
    constexpr int PSTR = 72;
    __shared__ bf16_t Ks[2][64 * 64];
    __shared__ bf16_t Vs[2][64 * 64];
    __shared__ bf16_t P_lds[8][16 * PSTR];

    const int t = threadIdx.x;
    const int lane = t & 63;
    const int w = t >> 6;                 // 0..7
    const int bh = blockIdx.x >> 4;       // 32 (b,h)
    const int qi = blockIdx.x & 15;
    const int qbH = 31 - qi, qbL = qi;
    const int qbC = (w < 4) ? qbH : qbL;  // this wave's chain
    const int q0 = qbC * 64 + (w & 3) * 16;
    const int b = bh >> 4, h = bh & 15;
    const int rr = lane & 15;
    const int hi = lane >> 4;

    const bf16_t* Kbh = Kg + (size_t)bh * S_DIM * DK;
    const bf16_t* Vbh = Vt + (size_t)bh * DK * S_DIM;   // [d][s]
    bf16_t* Pw = P_lds[w];

    // staging: 512 x 16B chunks per 8KB tile; 512 threads -> 1 chunk each.
    // LDS dest linear; global source pre-swizzled: col ^= (row&7)*8 elems.
    const int r0 = t >> 3, c0 = ((t & 7) ^ (r0 & 7)) * 8;

    // Q fragments, folded scale = (1/8) * log2(e)
    const float QSCALE = 0.18033688011112042f;
    const bf16_t* Qp = Q + ((size_t)bh * S_DIM + q0) * DK;
    bf16x8 qf[2];
    qf[0] = *reinterpret_cast<const bf16x8*>(&Qp[rr * DK + hi * 8]);
    qf[1] = *reinterpret_cast<const bf16x8*>(&Qp[rr * DK + 32 + hi * 8]);
#pragma unroll
    for (int i = 0; i < 8; ++i) {
        qf[0][i] = (__bf16)((float)qf[0][i] * QSCALE);
        qf[1][i] = (__bf16)((float)qf[1][i] * QSCALE);
    }

    bf16x8 ones;
#pragma unroll
    for (int i = 0; i < 8; ++i) ones[i] = (__bf16)1.0f;

    f32x4 o[4] = {};
    f32x4 la = {};
    float m = -INFINITY;

    const int ntH = qbH + 1;

    gload_lds16(Kbh + (size_t)r0 * DK + c0, &Ks[0][t * 8]);
    gload_lds16(Vbh + (size_t)r0 * S_DIM + c0, &Vs[0][t * 8]);
    __syncthreads();

    for (int tt = 0; tt < ntH; ++tt) {
        const int cur = tt & 1;
        const int kv0 = tt * 64;

        if (tt + 1 < ntH) {
            const int kv1 = kv0 + 64;
            gload_lds16(Kbh + (size_t)(kv1 + r0) * DK + c0, &Ks[cur ^ 1][t * 8]);
            gload_lds16(Vbh + (size_t)r0 * S_DIM + kv1 + c0, &Vs[cur ^ 1][t * 8]);
        }
        const bf16_t* Kc = Ks[cur];
        const bf16_t* Vc = Vs[cur];

        if (tt <= qbC) {
            // QK^T: s[t16][j] = S[kv = t16*16 + hi*4 + j][q = rr]
            f32x4 s[4] = {};
            __builtin_amdgcn_s_setprio(1);
#pragma unroll
            for (int t16 = 0; t16 < 4; ++t16) {
                const int r = t16 * 16 + rr;
                const int sw = (r & 7) * 8;
                bf16x8 kf0 = *reinterpret_cast<const bf16x8*>(&Kc[r * 64 + ((hi * 8) ^ sw)]);
                bf16x8 kf1 = *reinterpret_cast<const bf16x8*>(&Kc[r * 64 + ((32 + hi * 8) ^ sw)]);
                s[t16] = MFMA(kf0, qf[0], s[t16]);
                s[t16] = MFMA(kf1, qf[1], s[t16]);
            }
            __builtin_amdgcn_s_setprio(0);

            if (tt == qbC) {
                const int qg = q0 + rr;
#pragma unroll
                for (int t16 = 0; t16 < 4; ++t16)
#pragma unroll
                    for (int j = 0; j < 4; ++j)
                        if (kv0 + t16 * 16 + hi * 4 + j > qg) s[t16][j] = -INFINITY;
            }

            // softmax (lane-local defer-max trip, THR=8; l via ones-MFMA)
            f32x4 mv = s[0];
#pragma unroll
            for (int t16 = 1; t16 < 4; ++t16) {
                mv[0] = fmaxf(mv[0], s[t16][0]); mv[1] = fmaxf(mv[1], s[t16][1]);
                mv[2] = fmaxf(mv[2], s[t16][2]); mv[3] = fmaxf(mv[3], s[t16][3]);
            }
            const float mloc = fmaxf(fmaxf(mv[0], mv[1]), fmaxf(mv[2], mv[3]));
            if (__any(mloc - m > 8.0f)) {
                float mf = fmaxf(mloc, __shfl_xor(mloc, 16));
                mf = fmaxf(mf, __shfl_xor(mf, 32));
                const float mnew = fmaxf(m, mf);
                const float scale = exp2f(m - mnew);
#pragma unroll
                for (int i = 0; i < 4; ++i) la[i] *= scale;
#pragma unroll
                for (int db = 0; db < 4; ++db)
#pragma unroll
                    for (int j = 0; j < 4; ++j) o[db][j] *= scale;
                m = mnew;
            }
#pragma unroll
            for (int t16 = 0; t16 < 4; ++t16) {
                bf16x4 pb;
#pragma unroll
                for (int j = 0; j < 4; ++j) pb[j] = (__bf16)exp2f(s[t16][j] - m);
                *reinterpret_cast<bf16x4*>(&Pw[rr * PSTR + t16 * 16 + hi * 4]) = pb;
            }

            bf16x8 pf0 = *reinterpret_cast<const bf16x8*>(&Pw[rr * PSTR + hi * 8]);
            bf16x8 pf1 = *reinterpret_cast<const bf16x8*>(&Pw[rr * PSTR + 32 + hi * 8]);
            __builtin_amdgcn_s_setprio(1);
            la = MFMA(ones, pf0, la);
            la = MFMA(ones, pf1, la);
#pragma unroll
            for (int db = 0; db < 4; ++db) {
                const int vr = db * 16 + rr;
                const int sw = (vr & 7) * 8;
                bf16x8 vf0 = *reinterpret_cast<const bf16x8*>(&Vc[vr * 64 + ((hi * 8) ^ sw)]);
                bf16x8 vf1 = *reinterpret_cast<const bf16x8*>(&Vc[vr * 64 + ((32 + hi * 8) ^ sw)]);
                o[db] = MFMA(vf0, pf0, o[db]);
                o[db] = MFMA(vf1, pf1, o[db]);
            }
            __builtin_amdgcn_s_setprio(0);
        }

        __syncthreads();
    }

    const float linv = 1.0f / la[0];
#pragma unroll
    for (int db = 0; db < 4; ++db) {
        bf16x4 ov;
#pragma unroll
        for (int j = 0; j < 4; ++j) ov[j] = (__bf16)(o[db][j] * linv);
        *reinterpret_cast<bf16x4*>(
            &O[((size_t)(b * S_DIM + q0 + rr)) * DM + h * DK + db * 16 + hi * 4]) = ov;
    }
}

extern "C" void kernel_launch(void* const* d_in, const int* in_sizes, int n_in,
                              void* d_out, int out_size, void* d_ws, size_t ws_size,
                              hipStream_t stream) {
    const float* x  = (const float*)d_in[0];
    const float* Wq = (const float*)d_in[1];
    const float* Wk = (const float*)d_in[2];
    const float* Wv = (const float*)d_in[3];
    const float* Wo = (const float*)d_in[4];
    const int* pos  = (const int*)d_in[5];
    float* out = (float*)d_out;

    char* ws = (char*)d_ws;
    bf16_t* xb  = (bf16_t*)(ws);
    bf16_t* Wqb = (bf16_t*)(ws + (8u << 20));
    bf16_t* Wkb = (bf16_t*)(ws + (10u << 20));
    bf16_t* Wvb = (bf16_t*)(ws + (12u << 20));
    bf16_t* Wob = (bf16_t*)(ws + (14u << 20));
    bf16_t* Qb  = (bf16_t*)(ws + (16u << 20));
    bf16_t* Kb  = (bf16_t*)(ws + (24u << 20));
    bf16_t* Vtb = (bf16_t*)(ws + (32u << 20));
    bf16_t* Ab  = (bf16_t*)(ws);  // reuse xb region after QKV GEMM

    const int NX = B_DIM * S_DIM * DM;
    const int NW = DM * DM;
    const int NTOT = NX + 4 * NW;  // 8388608

    cvt_all<<<NTOT / 1024, 256, 0, stream>>>(x, Wq, Wk, Wv, Wo,
                                             xb, Wqb, Wkb, Wvb, Wob);

    gemm_bt<0><<<dim3(32, 8, 3), 256, 0, stream>>>(xb, Wqb, Wkb, Wvb,
                                                   Qb, Kb, Vtb, nullptr, pos);

    attn_kernel<<<B_DIM * H_DIM * 16, 512, 0, stream>>>(Qb, Kb, Vtb, Ab);

    gemm_bt<1><<<dim3(32, 8, 1), 256, 0, stream>>>(Ab, Wob, nullptr, nullptr,
                                                   nullptr, nullptr, nullptr, out, pos);
}

// Round 15
// 109.916 us; speedup vs baseline: 1.6473x; 1.0365x over previous
//
#include <hip/hip_runtime.h>
#include <hip/hip_bf16.h>
#include <math.h>

typedef __bf16 bf16_t;
typedef __attribute__((ext_vector_type(8))) __bf16 bf16x8;
typedef __attribute__((ext_vector_type(4))) __bf16 bf16x4;
typedef __attribute__((ext_vector_type(4))) float f32x4;

#define B_DIM 2
#define S_DIM 2048
#define H_DIM 16
#define DK 64
#define DM 1024
#define KDIM 1024

#define MFMA(a, b, c) __builtin_amdgcn_mfma_f32_16x16x32_bf16((a), (b), (c), 0, 0, 0)

__device__ __forceinline__ void gload_lds16(const bf16_t* g, bf16_t* l) {
    __builtin_amdgcn_global_load_lds(
        (const __attribute__((address_space(1))) void*)g,
        (__attribute__((address_space(3))) void*)l, 16, 0, 0);
}

// ---------------- fp32 -> bf16 convert: x + 4 weights in ONE launch ----------------
__global__ void cvt_all(const float* __restrict__ x,
                        const float* __restrict__ wq, const float* __restrict__ wk,
                        const float* __restrict__ wv, const float* __restrict__ wo,
                        bf16_t* __restrict__ xb,
                        bf16_t* __restrict__ wqb, bf16_t* __restrict__ wkb,
                        bf16_t* __restrict__ wvb, bf16_t* __restrict__ wob) {
    const long NX = (long)B_DIM * S_DIM * DM;       // 4194304
    const long i = ((long)blockIdx.x * 256 + threadIdx.x) * 4;
    const float* s; bf16_t* d; long off;
    if (i < NX) { s = x; d = xb; off = i; }
    else {
        const long j = i - NX;
        const int wsel = (int)(j >> 20);            // NW = 1<<20
        off = j & ((1L << 20) - 1);
        switch (wsel) {
            case 0: s = wq; d = wqb; break;
            case 1: s = wk; d = wkb; break;
            case 2: s = wv; d = wvb; break;
            default: s = wo; d = wob; break;
        }
    }
    float4 v = *reinterpret_cast<const float4*>(s + off);
    bf16x4 o;
    o[0] = (__bf16)v.x; o[1] = (__bf16)v.y; o[2] = (__bf16)v.z; o[3] = (__bf16)v.w;
    *reinterpret_cast<bf16x4*>(d + off) = o;
}

// ---------------- GEMM: Y[m,n] = sum_k A[m,k] * B[n,k]  (B^T layout) ----------------
// (unchanged from R12: BK=64 XOR-swizzled K-loop + coalesced epilogues)
template <int MODE>
__global__ __launch_bounds__(256)
void gemm_bt(const bf16_t* __restrict__ A,
             const bf16_t* __restrict__ B0,
             const bf16_t* __restrict__ B1,
             const bf16_t* __restrict__ B2,
             bf16_t* __restrict__ outQ,
             bf16_t* __restrict__ outK,
             bf16_t* __restrict__ outVt,
             float* __restrict__ outF,
             const int* __restrict__ pos) {
    constexpr int CP = 136;
    constexpr int SELEMS = (MODE == 0) ? (128 * CP) : 16384;
    __shared__ bf16_t smem[SELEMS];
    bf16_t* As = smem;            // [128][64] swizzled
    bf16_t* Bs = smem + 8192;     // [128][64] swizzled
    bf16_t* Cs = smem;            // epilogue overlay

    const int t = threadIdx.x;
    const int z = blockIdx.z;
    const bf16_t* Bm = (MODE == 0) ? (z == 0 ? B0 : (z == 1 ? B1 : B2)) : B0;

    const int m0 = blockIdx.x * 128;
    const int n0 = blockIdx.y * 128;
    const int lane = t & 63;
    const int w = t >> 6;
    const int wr = w >> 1;
    const int wc = w & 1;

    f32x4 acc[4][4] = {};

    const bf16_t* Ag = A + (size_t)m0 * KDIM;
    const bf16_t* Bg = Bm + (size_t)n0 * KDIM;

    const int rr = lane & 15;
    const int ko = (lane >> 4) * 8;

    int rI[4], cI[4];
#pragma unroll
    for (int c = 0; c < 4; ++c) {
        const int i = t + c * 256;
        rI[c] = i >> 3;
        cI[c] = ((i & 7) ^ (rI[c] & 7)) * 8;
    }

    for (int k0 = 0; k0 < KDIM; k0 += 64) {
#pragma unroll
        for (int c = 0; c < 4; ++c) {
            const int i = t + c * 256;
            gload_lds16(Ag + (size_t)rI[c] * KDIM + k0 + cI[c], &As[i * 8]);
        }
#pragma unroll
        for (int c = 0; c < 4; ++c) {
            const int i = t + c * 256;
            gload_lds16(Bg + (size_t)rI[c] * KDIM + k0 + cI[c], &Bs[i * 8]);
        }
        __syncthreads();

        bf16x8 af[2][4], bfr[2][4];
#pragma unroll
        for (int kk = 0; kk < 2; ++kk) {
#pragma unroll
            for (int m = 0; m < 4; ++m) {
                const int r = wr * 64 + m * 16 + rr;
                af[kk][m] = *reinterpret_cast<const bf16x8*>(
                    &As[r * 64 + ((kk * 32 + ko) ^ ((r & 7) * 8))]);
            }
#pragma unroll
            for (int n = 0; n < 4; ++n) {
                const int r = wc * 64 + n * 16 + rr;
                bfr[kk][n] = *reinterpret_cast<const bf16x8*>(
                    &Bs[r * 64 + ((kk * 32 + ko) ^ ((r & 7) * 8))]);
            }
        }
        __builtin_amdgcn_s_setprio(1);
#pragma unroll
        for (int kk = 0; kk < 2; ++kk)
#pragma unroll
            for (int m = 0; m < 4; ++m)
#pragma unroll
                for (int n = 0; n < 4; ++n)
                    acc[m][n] = MFMA(af[kk][m], bfr[kk][n], acc[m][n]);
        __builtin_amdgcn_s_setprio(0);
        __syncthreads();
    }

    const int rlb = wr * 64 + (lane >> 4) * 4;
    const int clb = wc * 64 + (lane & 15);

    if (MODE == 0) {
        if (z < 2) {
#pragma unroll
            for (int m = 0; m < 4; ++m)
#pragma unroll
                for (int n = 0; n < 4; ++n)
#pragma unroll
                    for (int j = 0; j < 4; ++j)
                        Cs[(rlb + m * 16 + j) * CP + clb + n * 16] = (__bf16)acc[m][n][j];
            __syncthreads();

            bf16_t* dst = (z == 0) ? outQ : outK;
            const int dch = t & 7;
            const int srow = t >> 3;
            float fr[4];
#pragma unroll
            for (int i = 0; i < 4; ++i)
                fr[i] = exp2f((float)(dch * 4 + i) * -0.4152410118609203f);
#pragma unroll
            for (int p = 0; p < 4; ++p) {
                const int s_loc = p * 32 + srow;
                const int gm = m0 + s_loc;
                const int bb = gm >> 11, sg = gm & (S_DIM - 1);
                const float pv = (float)pos[sg];
                float csv[4], snv[4];
#pragma unroll
                for (int i = 0; i < 4; ++i) {
                    const float a = pv * fr[i];
                    csv[i] = cosf(a); snv[i] = sinf(a);
                }
#pragma unroll
                for (int hc = 0; hc < 2; ++hc) {
                    const bf16x8 vv = *reinterpret_cast<const bf16x8*>(
                        &Cs[s_loc * CP + hc * 64 + dch * 8]);
                    bf16x8 ov;
#pragma unroll
                    for (int i = 0; i < 4; ++i) {
                        const float v0 = (float)vv[2 * i], v1 = (float)vv[2 * i + 1];
                        ov[2 * i]     = (__bf16)(v0 * csv[i] - v1 * snv[i]);
                        ov[2 * i + 1] = (__bf16)(v0 * snv[i] + v1 * csv[i]);
                    }
                    const int h = (n0 >> 6) + hc;
                    *reinterpret_cast<bf16x8*>(
                        &dst[((size_t)(bb * H_DIM + h) * S_DIM + sg) * 64 + dch * 8]) = ov;
                }
            }
        } else {
#pragma unroll
            for (int m = 0; m < 4; ++m)
#pragma unroll
                for (int n = 0; n < 4; ++n) {
                    const int cl = clb + n * 16;
                    bf16x4 v4;
#pragma unroll
                    for (int j = 0; j < 4; ++j) v4[j] = (__bf16)acc[m][n][j];
                    *reinterpret_cast<bf16x4*>(&Cs[cl * CP + rlb + m * 16]) = v4;
                }
            __syncthreads();

            const int cl = t >> 1, sh = t & 1;
            const int cg = n0 + cl, h = cg >> 6, d = cg & 63;
            const int bb = m0 >> 11, s0g = m0 & (S_DIM - 1);
            bf16_t* vdst = &outVt[((size_t)(bb * H_DIM + h) * DK + d) * S_DIM + s0g + sh * 64];
#pragma unroll
            for (int i = 0; i < 8; ++i)
                *reinterpret_cast<bf16x8*>(&vdst[i * 8]) =
                    *reinterpret_cast<const bf16x8*>(&Cs[cl * CP + sh * 64 + i * 8]);
        }
    } else {
        const int rbase = m0 + rlb;
        const int cbase = n0 + clb;
#pragma unroll
        for (int m = 0; m < 4; ++m)
#pragma unroll
            for (int n = 0; n < 4; ++n)
#pragma unroll
                for (int j = 0; j < 4; ++j)
                    outF[(size_t)(rbase + m * 16 + j) * DM + cbase + n * 16] = acc[m][n][j];
    }
}

// ---------------- causal flash attention v11: un-paired, 4 blocks/CU ----------------
// Block = 4 waves (256 thr) = ONE 64-row q-block; all waves active every tile.
// Grid 1024, longest-first. LDS = 2x8K (K) + 2x8K (V) + 4x2K (P) = 40960 B
// exactly -> 4 blocks/CU. P stored at stride 64 with XOR swizzle
// (col ^ (rr&7)*8) instead of padding — same swizzle family as K/V (proven).
__global__ __launch_bounds__(256, 4)
void attn_kernel(const bf16_t* __restrict__ Q, const bf16_t* __restrict__ Kg,
                 const bf16_t* __restrict__ Vt, bf16_t* __restrict__ O) {
    __shared__ bf16_t Ks[2][64 * 64];
    __shared__ bf16_t Vs[2][64 * 64];
    __shared__ bf16_t P_lds[4][16 * 64];

    const int t = threadIdx.x;
    const int lane = t & 63;
    const int w = t >> 6;                  // 0..3
    const int qbo = blockIdx.x >> 5;       // 0..31 (launch order: longest first)
    const int qb = 31 - qbo;
    const int bh = blockIdx.x & 31;
    const int q0 = qb * 64 + w * 16;
    const int b = bh >> 4, h = bh & 15;
    const int rr = lane & 15;
    const int hi = lane >> 4;
    const int psw = (rr & 7) * 8;          // P col XOR swizzle

    const bf16_t* Kbh = Kg + (size_t)bh * S_DIM * DK;
    const bf16_t* Vbh = Vt + (size_t)bh * DK * S_DIM;   // [d][s]
    bf16_t* Pw = P_lds[w];

    // staging: 512 x 16B chunks per 8KB tile; thread t does chunks t and t+256.
    // LDS dest linear; global source pre-swizzled: col ^= (row&7)*8 elems.
    const int i0 = t, i1 = t + 256;
    const int r0 = i0 >> 3, c0 = ((i0 & 7) ^ (r0 & 7)) * 8;
    const int r1 = i1 >> 3, c1 = ((i1 & 7) ^ (r1 & 7)) * 8;

    // Q fragments, folded scale = (1/8) * log2(e)
    const float QSCALE = 0.18033688011112042f;
    const bf16_t* Qp = Q + ((size_t)bh * S_DIM + q0) * DK;
    bf16x8 qf[2];
    qf[0] = *reinterpret_cast<const bf16x8*>(&Qp[rr * DK + hi * 8]);
    qf[1] = *reinterpret_cast<const bf16x8*>(&Qp[rr * DK + 32 + hi * 8]);
#pragma unroll
    for (int i = 0; i < 8; ++i) {
        qf[0][i] = (__bf16)((float)qf[0][i] * QSCALE);
        qf[1][i] = (__bf16)((float)qf[1][i] * QSCALE);
    }

    bf16x8 ones;
#pragma unroll
    for (int i = 0; i < 8; ++i) ones[i] = (__bf16)1.0f;

    f32x4 o[4] = {};
    f32x4 la = {};
    float m = -INFINITY;

    const int nt = qb + 1;

    gload_lds16(Kbh + (size_t)r0 * DK + c0, &Ks[0][i0 * 8]);
    gload_lds16(Kbh + (size_t)r1 * DK + c1, &Ks[0][i1 * 8]);
    gload_lds16(Vbh + (size_t)r0 * S_DIM + c0, &Vs[0][i0 * 8]);
    gload_lds16(Vbh + (size_t)r1 * S_DIM + c1, &Vs[0][i1 * 8]);
    __syncthreads();

    for (int tt = 0; tt < nt; ++tt) {
        const int cur = tt & 1;
        const int kv0 = tt * 64;

        if (tt + 1 < nt) {
            const int kv1 = kv0 + 64;
            bf16_t* Kn = Ks[cur ^ 1];
            bf16_t* Vn = Vs[cur ^ 1];
            gload_lds16(Kbh + (size_t)(kv1 + r0) * DK + c0, &Kn[i0 * 8]);
            gload_lds16(Kbh + (size_t)(kv1 + r1) * DK + c1, &Kn[i1 * 8]);
            gload_lds16(Vbh + (size_t)r0 * S_DIM + kv1 + c0, &Vn[i0 * 8]);
            gload_lds16(Vbh + (size_t)r1 * S_DIM + kv1 + c1, &Vn[i1 * 8]);
        }
        const bf16_t* Kc = Ks[cur];
        const bf16_t* Vc = Vs[cur];

        // QK^T: s[t16][j] = S[kv = t16*16 + hi*4 + j][q = rr]
        f32x4 s[4] = {};
        __builtin_amdgcn_s_setprio(1);
#pragma unroll
        for (int t16 = 0; t16 < 4; ++t16) {
            const int r = t16 * 16 + rr;
            const int sw = (r & 7) * 8;
            bf16x8 kf0 = *reinterpret_cast<const bf16x8*>(&Kc[r * 64 + ((hi * 8) ^ sw)]);
            bf16x8 kf1 = *reinterpret_cast<const bf16x8*>(&Kc[r * 64 + ((32 + hi * 8) ^ sw)]);
            s[t16] = MFMA(kf0, qf[0], s[t16]);
            s[t16] = MFMA(kf1, qf[1], s[t16]);
        }
        __builtin_amdgcn_s_setprio(0);

        if (tt == qb) {
            const int qg = q0 + rr;
#pragma unroll
            for (int t16 = 0; t16 < 4; ++t16)
#pragma unroll
                for (int j = 0; j < 4; ++j)
                    if (kv0 + t16 * 16 + hi * 4 + j > qg) s[t16][j] = -INFINITY;
        }

        // softmax (lane-local defer-max trip, THR=8; l via ones-MFMA)
        f32x4 mv = s[0];
#pragma unroll
        for (int t16 = 1; t16 < 4; ++t16) {
            mv[0] = fmaxf(mv[0], s[t16][0]); mv[1] = fmaxf(mv[1], s[t16][1]);
            mv[2] = fmaxf(mv[2], s[t16][2]); mv[3] = fmaxf(mv[3], s[t16][3]);
        }
        const float mloc = fmaxf(fmaxf(mv[0], mv[1]), fmaxf(mv[2], mv[3]));
        if (__any(mloc - m > 8.0f)) {
            float mf = fmaxf(mloc, __shfl_xor(mloc, 16));
            mf = fmaxf(mf, __shfl_xor(mf, 32));
            const float mnew = fmaxf(m, mf);
            const float scale = exp2f(m - mnew);
#pragma unroll
            for (int i = 0; i < 4; ++i) la[i] *= scale;
#pragma unroll
            for (int db = 0; db < 4; ++db)
#pragma unroll
                for (int j = 0; j < 4; ++j) o[db][j] *= scale;
            m = mnew;
        }
#pragma unroll
        for (int t16 = 0; t16 < 4; ++t16) {
            bf16x4 pb;
#pragma unroll
            for (int j = 0; j < 4; ++j) pb[j] = (__bf16)exp2f(s[t16][j] - m);
            *reinterpret_cast<bf16x4*>(&Pw[rr * 64 + ((t16 * 16 + hi * 4) ^ psw)]) = pb;
        }

        bf16x8 pf0 = *reinterpret_cast<const bf16x8*>(&Pw[rr * 64 + ((hi * 8) ^ psw)]);
        bf16x8 pf1 = *reinterpret_cast<const bf16x8*>(&Pw[rr * 64 + ((32 + hi * 8) ^ psw)]);
        __builtin_amdgcn_s_setprio(1);
        la = MFMA(ones, pf0, la);
        la = MFMA(ones, pf1, la);
#pragma unroll
        for (int db = 0; db < 4; ++db) {
            const int vr = db * 16 + rr;
            const int sw = (vr & 7) * 8;
            bf16x8 vf0 = *reinterpret_cast<const bf16x8*>(&Vc[vr * 64 + ((hi * 8) ^ sw)]);
            bf16x8 vf1 = *reinterpret_cast<const bf16x8*>(&Vc[vr * 64 + ((32 + hi * 8) ^ sw)]);
            o[db] = MFMA(vf0, pf0, o[db]);
            o[db] = MFMA(vf1, pf1, o[db]);
        }
        __builtin_amdgcn_s_setprio(0);

        __syncthreads();
    }

    const float linv = 1.0f / la[0];
#pragma unroll
    for (int db = 0; db < 4; ++db) {
        bf16x4 ov;
#pragma unroll
        for (int j = 0; j < 4; ++j) ov[j] = (__bf16)(o[db][j] * linv);
        *reinterpret_cast<bf16x4*>(
            &O[((size_t)(b * S_DIM + q0 + rr)) * DM + h * DK + db * 16 + hi * 4]) = ov;
    }
}

extern "C" void kernel_launch(void* const* d_in, const int* in_sizes, int n_in,
                              void* d_out, int out_size, void* d_ws, size_t ws_size,
                              hipStream_t stream) {
    const float* x  = (const float*)d_in[0];
    const float* Wq = (const float*)d_in[1];
    const float* Wk = (const float*)d_in[2];
    const float* Wv = (const float*)d_in[3];
    const float* Wo = (const float*)d_in[4];
    const int* pos  = (const int*)d_in[5];
    float* out = (float*)d_out;

    char* ws = (char*)d_ws;
    bf16_t* xb  = (bf16_t*)(ws);
    bf16_t* Wqb = (bf16_t*)(ws + (8u << 20));
    bf16_t* Wkb = (bf16_t*)(ws + (10u << 20));
    bf16_t* Wvb = (bf16_t*)(ws + (12u << 20));
    bf16_t* Wob = (bf16_t*)(ws + (14u << 20));
    bf16_t* Qb  = (bf16_t*)(ws + (16u << 20));
    bf16_t* Kb  = (bf16_t*)(ws + (24u << 20));
    bf16_t* Vtb = (bf16_t*)(ws + (32u << 20));
    bf16_t* Ab  = (bf16_t*)(ws);  // reuse xb region after QKV GEMM

    const int NX = B_DIM * S_DIM * DM;
    const int NW = DM * DM;
    const int NTOT = NX + 4 * NW;  // 8388608

    cvt_all<<<NTOT / 1024, 256, 0, stream>>>(x, Wq, Wk, Wv, Wo,
                                             xb, Wqb, Wkb, Wvb, Wob);

    gemm_bt<0><<<dim3(32, 8, 3), 256, 0, stream>>>(xb, Wqb, Wkb, Wvb,
                                                   Qb, Kb, Vtb, nullptr, pos);

    attn_kernel<<<B_DIM * H_DIM * 32, 256, 0, stream>>>(Qb, Kb, Vtb, Ab);

    gemm_bt<1><<<dim3(32, 8, 1), 256, 0, stream>>>(Ab, Wob, nullptr, nullptr,
                                                   nullptr, nullptr, nullptr, out, pos);
}